// Round 11
// baseline (137.007 us; speedup 1.0000x reference)
//
#include <hip/hip_runtime.h>
#include <stdint.h>

#define NTOK 4096
#define CDIM 512
#define HEADS 8
#define DHEAD 64
#define PHEAD (NTOK * DHEAD)          // 262144 elems per head per tensor

typedef __bf16 bf16x8 __attribute__((ext_vector_type(8)));
typedef float f32x4 __attribute__((ext_vector_type(4)));

typedef const __attribute__((address_space(1))) unsigned int* gas_ptr;
typedef __attribute__((address_space(3))) unsigned int* las_ptr;

__device__ __forceinline__ unsigned short bfbits(float f) {
    return __builtin_bit_cast(unsigned short, (__bf16)f);   // hw v_cvt on gfx950
}

__device__ __forceinline__ f32x4 mfma32(bf16x8 a, bf16x8 b, f32x4 c) {
    return __builtin_amdgcn_mfma_f32_16x16x32_bf16(a, b, c, 0, 0, 0);
}

// async global->LDS, 16 B per lane (wave-uniform LDS base + lane*16, linear dest)
__device__ __forceinline__ void gload16(const unsigned short* g, unsigned short* l) {
    __builtin_amdgcn_global_load_lds((gas_ptr)g, (las_ptr)l, 16, 0, 0);
}

// cvt 8 fp32 (in regs) -> 8 bf16, single 16B store
__device__ __forceinline__ void cvt_store8(unsigned short* dst, float4 v0, float4 v1) {
    unsigned short o[8];
    o[0] = bfbits(v0.x); o[1] = bfbits(v0.y); o[2] = bfbits(v0.z); o[3] = bfbits(v0.w);
    o[4] = bfbits(v1.x); o[5] = bfbits(v1.y); o[6] = bfbits(v1.z); o[7] = bfbits(v1.w);
    *(uint4*)dst = *(const uint4*)o;
}

// ---------------- pre-cast: x / Wqkv / Wproj fp32 -> bf16 (one pass, ~18 MB) ----------------
__global__ __launch_bounds__(256) void cast3_k(
    const float* __restrict__ x, const float* __restrict__ wq, const float* __restrict__ wp,
    unsigned short* __restrict__ xb, unsigned short* __restrict__ wqb,
    unsigned short* __restrict__ wpb)
{
    const int b = blockIdx.x;
    const float* src; unsigned short* dst; int off;
    if (b < 1024)      { src = x;  dst = xb;  off = b; }          // 4096*512 = 1024 blk
    else if (b < 1408) { src = wq; dst = wqb; off = b - 1024; }   // 1536*512 = 384 blk
    else               { src = wp; dst = wpb; off = b - 1408; }   // 512*512  = 128 blk
    const int i = (off * 256 + threadIdx.x) * 8;
    const float4 v0 = *(const float4*)(src + i);
    const float4 v1 = *(const float4*)(src + i + 4);
    cvt_store8(dst + i, v0, v1);
}

// ---------------- QKV GEMM: 64x128, dbuf gload_lds, bank-swizzled reads (round-9) ----------
__global__ __launch_bounds__(256) void gemm_qkv(
    const unsigned short* __restrict__ A,   // x bf16 [4096][512]
    const unsigned short* __restrict__ Bm,  // Wqkv bf16 [1536][512]
    const float* __restrict__ bias,
    const float* __restrict__ scale_p,
    unsigned short* __restrict__ qkv_out)
{
    // 2 bufs x (lA 2048 + lB 4096 shorts) = 24576 B; epilogue reuses first 17408 B
    __shared__ __align__(16) unsigned short smem[2 * 6144];

    const int tid = threadIdx.x;
    const int mBase = blockIdx.y * 64, nBase = blockIdx.x * 128;
    const int lane = tid & 63;
    const int w = __builtin_amdgcn_readfirstlane(tid >> 6);
    const int l16 = lane & 15, quad = lane >> 4;

    const int srow = tid >> 2;
    const int scol = ((tid & 3) ^ ((tid >> 3) & 3)) * 8;     // pre-swizzled source granule
    const unsigned short* gA  = &A[(size_t)(mBase + srow) * CDIM + scol];
    const unsigned short* gB0 = &Bm[(size_t)(nBase + srow) * CDIM + scol];
    const unsigned short* gB1 = &Bm[(size_t)(nBase + 64 + srow) * CDIM + scol];

    const int qs = (quad ^ ((l16 >> 1) & 3)) * 8;            // swizzled read granule

    f32x4 acc[4][2] = {};   // wave w owns cols [w*32, w*32+32), all 64 rows

    // prologue: stage tile 0 into buf 0
    gload16(gA, &smem[tid * 8]);
    gload16(gB0, &smem[2048 + tid * 8]);
    gload16(gB1, &smem[4096 + tid * 8]);

    int cur = 0;
    for (int kt = 0; kt < CDIM; kt += 32) {
        __syncthreads();        // drains prefetch (buf[cur] ready); prior buf[cur^1] reads done
        if (kt + 32 < CDIM) {
            const int nb = (cur ^ 1) * 6144;
            gload16(gA + kt + 32, &smem[nb + tid * 8]);
            gload16(gB0 + kt + 32, &smem[nb + 2048 + tid * 8]);
            gload16(gB1 + kt + 32, &smem[nb + 4096 + tid * 8]);
        }
        const unsigned short* lA = &smem[cur * 6144];
        const unsigned short* lB = &smem[cur * 6144 + 2048];

        bf16x8 af[4], bfr[2];
#pragma unroll
        for (int i = 0; i < 4; ++i)
            af[i] = *(const bf16x8*)&lA[(i * 16 + l16) * 32 + qs];
#pragma unroll
        for (int j = 0; j < 2; ++j)
            bfr[j] = *(const bf16x8*)&lB[(w * 32 + j * 16 + l16) * 32 + qs];
#pragma unroll
        for (int i = 0; i < 4; ++i)
#pragma unroll
            for (int j = 0; j < 2; ++j)
                acc[i][j] = mfma32(af[i], bfr[j], acc[i][j]);
        cur ^= 1;
    }

    const int three = nBase >> 9;               // block-uniform: 0 q, 1 k, 2 v
    const float scl = scale_p[0] * 1.44269504f; // fold log2(e)
    const float mul = (three == 0) ? scl : 1.0f;

    __syncthreads();
#pragma unroll
    for (int i = 0; i < 4; ++i)
#pragma unroll
        for (int j = 0; j < 2; ++j)
#pragma unroll
            for (int r = 0; r < 4; ++r) {
                const int rl = i * 16 + quad * 4 + r;
                const int cl = w * 32 + j * 16 + l16;
                const float v = (acc[i][j][r] + bias[nBase + cl]) * mul;
                smem[rl * 136 + cl] = bfbits(v);
            }
    __syncthreads();

    const size_t base3 = (size_t)three * (PHEAD * HEADS);
    if (three < 2) {
        // Q/K frag layout [h][t16][d2][quad*16+l16][8]
#pragma unroll
        for (int pass = 0; pass < 4; ++pass) {
            const int idx = pass * 256 + tid;
            const int rl16 = idx & 15, qc = (idx >> 4) & 7;
            const int hsel = (idx >> 7) & 1, t16l = (idx >> 8) & 3;
            const uint4 d = *(const uint4*)&smem[(t16l * 16 + rl16) * 136 + hsel * 64 + qc * 8];
            const int hh = ((nBase >> 6) + hsel) & 7;
            const int t16 = (mBase >> 4) + t16l;
            const size_t dst = base3 + (size_t)hh * PHEAD +
                (size_t)(((t16 * 2 + (qc >> 2)) * 64 + (qc & 3) * 16 + rl16) * 8);
            *(uint4*)&qkv_out[dst] = d;
        }
    } else {
        // V frag layout [h][k32][dt][quad*16+l16][8] (key-permuted for PV mfma32)
#pragma unroll
        for (int pass = 0; pass < 4; ++pass) {
            const int idx = pass * 256 + tid;
            const int l16t = idx & 15, quadt = (idx >> 4) & 3;
            const int dt = (idx >> 6) & 3, k32l = (idx >> 8) & 1, hsel = (idx >> 9) & 1;
            const int col = hsel * 64 + dt * 16 + l16t;
            unsigned short o8[8];
#pragma unroll
            for (int e = 0; e < 4; ++e) {
                o8[e]     = smem[(k32l * 32 + quadt * 4 + e) * 136 + col];
                o8[e + 4] = smem[(k32l * 32 + 16 + quadt * 4 + e) * 136 + col];
            }
            const int hh = ((nBase >> 6) + hsel) & 7;
            const int k32 = (mBase >> 5) + k32l;
            const size_t dst = base3 + (size_t)hh * PHEAD +
                (size_t)(((k32 * 4 + dt) * 64 + quadt * 16 + l16t) * 8);
            *(uint4*)&qkv_out[dst] = *(uint4*)o8;
        }
    }
}

// ---------------- flash attention v13: LDS-staged K/V double-buffer (latency hidden) --------
// Per wave: private 8 KB staging region per buffer (K 4 KB + V 4 KB), gload16 DMA.
// Loop: barrier (buf[cur] ready) -> STAGE(g+1) flies under compute -> ds_read K -> QK ->
//       SM -> ds_read V -> PV. Zero VGPR spent on K/V buffers. Math identical to flash8.
__global__ __launch_bounds__(256, 2) void flash13_k(
    const unsigned short* __restrict__ qf,
    const unsigned short* __restrict__ kf,
    const unsigned short* __restrict__ vf,
    unsigned short* __restrict__ attn_out)   // [N][C] bf16
{
    __shared__ __align__(16) char sbuf[65536];   // 2 bufs x 4 waves x 8 KB

    const int tid = threadIdx.x;
    const int lane = tid & 63;
    const int w = __builtin_amdgcn_readfirstlane(tid >> 6);
    const int l16 = lane & 15, quad = lane >> 4;
    const int h = blockIdx.x, qb = blockIdx.y;     // XCD swizzle: x = head

    const unsigned short* qh = qf + (size_t)h * PHEAD;
    const unsigned short* kb = kf + (size_t)h * PHEAD + w * 65536;   // 1024 keys/wave
    const unsigned short* vb = vf + (size_t)h * PHEAD + w * 65536;

    bf16x8 qfr[4][2];
#pragma unroll
    for (int qt = 0; qt < 4; ++qt)
#pragma unroll
        for (int d2 = 0; d2 < 2; ++d2)
            qfr[qt][d2] = *(const bf16x8*)&qh[((qb * 4 + qt) * 2 + d2) * 512 + lane * 8];

    f32x4 oacc[4][4] = {};   // [dtile][qtile]: O^T  d=quad*4+r, q=l16
    float lv[4] = {};        // per-lane partial l, quad-reduced at end

    unsigned short* stg = (unsigned short*)sbuf + w * 4096;   // wave region (shorts)

    auto STAGE = [&](int b, int g) {
        unsigned short* s = stg + b * 16384;        // buf stride 32768 B
#pragma unroll
        for (int i = 0; i < 4; ++i) {
            gload16(&kb[g * 2048 + i * 512 + lane * 8], &s[i * 512 + lane * 8]);
            gload16(&vb[g * 2048 + i * 512 + lane * 8], &s[2048 + i * 512 + lane * 8]);
        }
    };

    STAGE(0, 0);
    int cur = 0;
    for (int g = 0; g < 32; ++g) {
        __syncthreads();                       // buf[cur] resident; buf[cur^1] reads done
        if (g + 1 < 32) STAGE(cur ^ 1, g + 1); // next tile's DMA flies under this compute
        const unsigned short* s = stg + cur * 16384;

        bf16x8 kk[4];
#pragma unroll
        for (int i = 0; i < 4; ++i)
            kk[i] = *(const bf16x8*)&s[i * 512 + lane * 8];

        f32x4 s0[4], s1[4];
        __builtin_amdgcn_s_setprio(1);
#pragma unroll
        for (int qt = 0; qt < 4; ++qt) {
            f32x4 a = {};
            a = mfma32(kk[0], qfr[qt][0], a);
            a = mfma32(kk[1], qfr[qt][1], a);
            s0[qt] = a;
            f32x4 b = {};
            b = mfma32(kk[2], qfr[qt][0], b);
            b = mfma32(kk[3], qfr[qt][1], b);
            s1[qt] = b;
        }
        __builtin_amdgcn_s_setprio(0);

        bf16x8 pf[4];
#pragma unroll
        for (int qt = 0; qt < 4; ++qt) {
            float e0[4], e1[4];
#pragma unroll
            for (int r = 0; r < 4; ++r) {
                e0[r] = __builtin_amdgcn_exp2f(s0[qt][r]);
                e1[r] = __builtin_amdgcn_exp2f(s1[qt][r]);
            }
            lv[qt] += ((e0[0] + e0[1]) + (e0[2] + e0[3])) +
                      ((e1[0] + e1[1]) + (e1[2] + e1[3]));
            bf16x8 pb;
#pragma unroll
            for (int r = 0; r < 4; ++r) {
                pb[r]     = (__bf16)e0[r];
                pb[4 + r] = (__bf16)e1[r];
            }
            pf[qt] = pb;
        }

        bf16x8 vv[4];
#pragma unroll
        for (int i = 0; i < 4; ++i)
            vv[i] = *(const bf16x8*)&s[2048 + i * 512 + lane * 8];

        __builtin_amdgcn_s_setprio(1);
#pragma unroll
        for (int dt = 0; dt < 4; ++dt)
#pragma unroll
            for (int qt = 0; qt < 4; ++qt)
                oacc[dt][qt] = mfma32(vv[dt], pf[qt], oacc[dt][qt]);
        __builtin_amdgcn_s_setprio(0);
        cur ^= 1;
    }

    __syncthreads();   // all staging reads done before epilogue reuses sbuf

    // epilogue: 2 chunks of 32 q-rows, ldsO[4][32][68] + sml[4][64] reuse staging LDS
    float (*ldsO)[32][68] = (float(*)[32][68])sbuf;            // 34816 B
    float (*sml)[64]      = (float(*)[64])(sbuf + 34816);      //  1024 B

#pragma unroll
    for (int qt = 0; qt < 4; ++qt) {
        float L = lv[qt];
        L += __shfl_xor(L, 16, 64);
        L += __shfl_xor(L, 32, 64);
        if (quad == 0) sml[w][qt * 16 + l16] = L;
    }

#pragma unroll
    for (int c = 0; c < 2; ++c) {
#pragma unroll
        for (int qh2 = 0; qh2 < 2; ++qh2) {
            const int qt = c * 2 + qh2;
            const int qrow = qh2 * 16 + l16;
#pragma unroll
            for (int dt = 0; dt < 4; ++dt)
                *(f32x4*)&ldsO[w][qrow][dt * 16 + quad * 4] = oacc[dt][qt];
        }
        __syncthreads();
        {
            const int ql = tid >> 3, dseg = (tid & 7) * 8;     // 32 rows x 8 col-segments
            const int q = c * 32 + ql;
            const float L = sml[0][q] + sml[1][q] + sml[2][q] + sml[3][q];
            const float inv = 1.f / L;
            unsigned short o8[8];
#pragma unroll
            for (int i = 0; i < 8; ++i) {
                const float v = ldsO[0][ql][dseg + i] + ldsO[1][ql][dseg + i] +
                                ldsO[2][ql][dseg + i] + ldsO[3][ql][dseg + i];
                o8[i] = bfbits(v * inv);
            }
            *(uint4*)&attn_out[(size_t)(qb * 64 + q) * CDIM + h * DHEAD + dseg] = *(uint4*)o8;
        }
        __syncthreads();   // chunk reads done before next chunk's writes
    }
}

// ---------------- proj GEMM: 64x64, dbuf gload_lds, bank-swizzled reads (round-9) ----------
__global__ __launch_bounds__(256) void gemm_proj(
    const unsigned short* __restrict__ A,   // attn [4096][512] bf16
    const unsigned short* __restrict__ Bm,  // Wproj bf16 [512][512]
    const float* __restrict__ bias,
    float* __restrict__ c_out)              // [4096][512] fp32
{
    __shared__ __align__(16) unsigned short smem[2 * 4096];  // 16384 B

    const int tid = threadIdx.x;
    const int mBase = blockIdx.y * 64, nBase = blockIdx.x * 64;
    const int lane = tid & 63;
    const int w = __builtin_amdgcn_readfirstlane(tid >> 6);
    const int l16 = lane & 15, quad = lane >> 4;

    const int srow = tid >> 2;
    const int scol = ((tid & 3) ^ ((tid >> 3) & 3)) * 8;     // pre-swizzled source granule
    const unsigned short* gA = &A[(size_t)(mBase + srow) * CDIM + scol];
    const unsigned short* gB = &Bm[(size_t)(nBase + srow) * CDIM + scol];

    const int qs = (quad ^ ((l16 >> 1) & 3)) * 8;            // swizzled read granule

    f32x4 acc[4] = {};   // wave w owns cols [w*16, w*16+16), all 64 rows

    gload16(gA, &smem[tid * 8]);
    gload16(gB, &smem[2048 + tid * 8]);

    int cur = 0;
    for (int kt = 0; kt < CDIM; kt += 32) {
        __syncthreads();
        if (kt + 32 < CDIM) {
            const int nb = (cur ^ 1) * 4096;
            gload16(gA + kt + 32, &smem[nb + tid * 8]);
            gload16(gB + kt + 32, &smem[nb + 2048 + tid * 8]);
        }
        const unsigned short* lA = &smem[cur * 4096];
        const unsigned short* lB = &smem[cur * 4096 + 2048];

        bf16x8 af[4], bfr;
#pragma unroll
        for (int i = 0; i < 4; ++i)
            af[i] = *(const bf16x8*)&lA[(i * 16 + l16) * 32 + qs];
        bfr = *(const bf16x8*)&lB[(w * 16 + l16) * 32 + qs];
#pragma unroll
        for (int i = 0; i < 4; ++i)
            acc[i] = mfma32(af[i], bfr, acc[i]);
        cur ^= 1;
    }

#pragma unroll
    for (int i = 0; i < 4; ++i)
#pragma unroll
        for (int r = 0; r < 4; ++r) {
            const int grow = mBase + i * 16 + quad * 4 + r;
            const int gcol = nBase + w * 16 + l16;
            c_out[(size_t)grow * CDIM + gcol] = acc[i][r] + bias[gcol];
        }
}

extern "C" void kernel_launch(void* const* d_in, const int* in_sizes, int n_in,
                              void* d_out, int out_size, void* d_ws, size_t ws_size,
                              hipStream_t stream) {
    const float* x       = (const float*)d_in[0];
    const float* scale_p = (const float*)d_in[3];
    const float* Wqkv    = (const float*)d_in[4];
    const float* bqkv    = (const float*)d_in[5];
    const float* Wproj   = (const float*)d_in[6];
    const float* bproj   = (const float*)d_in[7];
    float* out = (float*)d_out;

    char* ws = (char*)d_ws;
    const size_t OFF_QKV  = 0;                        // 3*8*PHEAD bf16 = 12 MB
    const size_t OFF_ATTN = 12582912;                 // 4096*512 bf16  =  4 MB
    const size_t OFF_XB   = 16777216;                 // x bf16          =  4 MB
    const size_t OFF_WQB  = 20971520;                 // Wqkv bf16       = 1.5 MB
    const size_t OFF_WPB  = 22544384;                 // Wproj bf16      = 0.5 MB
    const size_t NEEDED   = OFF_WPB + 524288;         // 23 MB
    if (ws_size < NEEDED) return;

    unsigned short* qkvb  = (unsigned short*)(ws + OFF_QKV);
    unsigned short* attnb = (unsigned short*)(ws + OFF_ATTN);
    unsigned short* xb    = (unsigned short*)(ws + OFF_XB);
    unsigned short* wqb   = (unsigned short*)(ws + OFF_WQB);
    unsigned short* wpb   = (unsigned short*)(ws + OFF_WPB);

    cast3_k<<<1536, 256, 0, stream>>>(x, Wqkv, Wproj, xb, wqb, wpb);

    gemm_qkv<<<dim3(12, 64), 256, 0, stream>>>(xb, wqb, bqkv, scale_p, qkvb);

    const unsigned short* qfr = qkvb;
    const unsigned short* kfr = qkvb + (size_t)PHEAD * HEADS;
    const unsigned short* vfr = qkvb + (size_t)2 * PHEAD * HEADS;
    flash13_k<<<dim3(8, 64), 256, 0, stream>>>(qfr, kfr, vfr, attnb);

    gemm_proj<<<dim3(8, 64), 256, 0, stream>>>(attnb, wpb, bproj, out);
}

// Round 12
// 128.111 us; speedup vs baseline: 1.0694x; 1.0694x over previous
//
#include <hip/hip_runtime.h>
#include <stdint.h>

#define NTOK 4096
#define CDIM 512
#define HEADS 8
#define DHEAD 64
#define PHEAD (NTOK * DHEAD)          // 262144 elems per head per tensor

typedef __bf16 bf16x8 __attribute__((ext_vector_type(8)));
typedef float f32x4 __attribute__((ext_vector_type(4)));

typedef const __attribute__((address_space(1))) unsigned int* gas_ptr;
typedef __attribute__((address_space(3))) unsigned int* las_ptr;

__device__ __forceinline__ unsigned short bfbits(float f) {
    return __builtin_bit_cast(unsigned short, (__bf16)f);   // hw v_cvt on gfx950
}

__device__ __forceinline__ f32x4 mfma32(bf16x8 a, bf16x8 b, f32x4 c) {
    return __builtin_amdgcn_mfma_f32_16x16x32_bf16(a, b, c, 0, 0, 0);
}

// async global->LDS, 16 B per lane (wave-uniform LDS base + lane*16, linear dest)
__device__ __forceinline__ void gload16(const unsigned short* g, unsigned short* l) {
    __builtin_amdgcn_global_load_lds((gas_ptr)g, (las_ptr)l, 16, 0, 0);
}

// cvt 8 fp32 (in regs) -> 8 bf16, single 16B store
__device__ __forceinline__ void cvt_store8(unsigned short* dst, float4 v0, float4 v1) {
    unsigned short o[8];
    o[0] = bfbits(v0.x); o[1] = bfbits(v0.y); o[2] = bfbits(v0.z); o[3] = bfbits(v0.w);
    o[4] = bfbits(v1.x); o[5] = bfbits(v1.y); o[6] = bfbits(v1.z); o[7] = bfbits(v1.w);
    *(uint4*)dst = *(const uint4*)o;
}

// ---------------- pre-cast: x / Wqkv / Wproj fp32 -> bf16 (one pass, ~18 MB) ----------------
__global__ __launch_bounds__(256) void cast3_k(
    const float* __restrict__ x, const float* __restrict__ wq, const float* __restrict__ wp,
    unsigned short* __restrict__ xb, unsigned short* __restrict__ wqb,
    unsigned short* __restrict__ wpb)
{
    const int b = blockIdx.x;
    const float* src; unsigned short* dst; int off;
    if (b < 1024)      { src = x;  dst = xb;  off = b; }          // 4096*512 = 1024 blk
    else if (b < 1408) { src = wq; dst = wqb; off = b - 1024; }   // 1536*512 = 384 blk
    else               { src = wp; dst = wpb; off = b - 1408; }   // 512*512  = 128 blk
    const int i = (off * 256 + threadIdx.x) * 8;
    const float4 v0 = *(const float4*)(src + i);
    const float4 v1 = *(const float4*)(src + i + 4);
    cvt_store8(dst + i, v0, v1);
}

// ---------------- QKV GEMM: 64x128, dbuf gload_lds, bank-swizzled reads --------------------
__global__ __launch_bounds__(256) void gemm_qkv(
    const unsigned short* __restrict__ A,   // x bf16 [4096][512]
    const unsigned short* __restrict__ Bm,  // Wqkv bf16 [1536][512]
    const float* __restrict__ bias,
    const float* __restrict__ scale_p,
    unsigned short* __restrict__ qkv_out)
{
    // 2 bufs x (lA 2048 + lB 4096 shorts) = 24576 B; epilogue reuses first 17408 B
    __shared__ __align__(16) unsigned short smem[2 * 6144];

    const int tid = threadIdx.x;
    const int mBase = blockIdx.y * 64, nBase = blockIdx.x * 128;
    const int lane = tid & 63;
    const int w = __builtin_amdgcn_readfirstlane(tid >> 6);
    const int l16 = lane & 15, quad = lane >> 4;

    const int srow = tid >> 2;
    const int scol = ((tid & 3) ^ ((tid >> 3) & 3)) * 8;     // pre-swizzled source granule
    const unsigned short* gA  = &A[(size_t)(mBase + srow) * CDIM + scol];
    const unsigned short* gB0 = &Bm[(size_t)(nBase + srow) * CDIM + scol];
    const unsigned short* gB1 = &Bm[(size_t)(nBase + 64 + srow) * CDIM + scol];

    const int qs = (quad ^ ((l16 >> 1) & 3)) * 8;            // swizzled read granule

    f32x4 acc[4][2] = {};   // wave w owns cols [w*32, w*32+32), all 64 rows

    // prologue: stage tile 0 into buf 0
    gload16(gA, &smem[tid * 8]);
    gload16(gB0, &smem[2048 + tid * 8]);
    gload16(gB1, &smem[4096 + tid * 8]);

    int cur = 0;
    for (int kt = 0; kt < CDIM; kt += 32) {
        __syncthreads();        // drains prefetch (buf[cur] ready); prior buf[cur^1] reads done
        if (kt + 32 < CDIM) {
            const int nb = (cur ^ 1) * 6144;
            gload16(gA + kt + 32, &smem[nb + tid * 8]);
            gload16(gB0 + kt + 32, &smem[nb + 2048 + tid * 8]);
            gload16(gB1 + kt + 32, &smem[nb + 4096 + tid * 8]);
        }
        const unsigned short* lA = &smem[cur * 6144];
        const unsigned short* lB = &smem[cur * 6144 + 2048];

        bf16x8 af[4], bfr[2];
#pragma unroll
        for (int i = 0; i < 4; ++i)
            af[i] = *(const bf16x8*)&lA[(i * 16 + l16) * 32 + qs];
#pragma unroll
        for (int j = 0; j < 2; ++j)
            bfr[j] = *(const bf16x8*)&lB[(w * 32 + j * 16 + l16) * 32 + qs];
#pragma unroll
        for (int i = 0; i < 4; ++i)
#pragma unroll
            for (int j = 0; j < 2; ++j)
                acc[i][j] = mfma32(af[i], bfr[j], acc[i][j]);
        cur ^= 1;
    }

    const int three = nBase >> 9;               // block-uniform: 0 q, 1 k, 2 v
    const float scl = scale_p[0] * 1.44269504f; // fold log2(e)
    const float mul = (three == 0) ? scl : 1.0f;

    __syncthreads();
#pragma unroll
    for (int i = 0; i < 4; ++i)
#pragma unroll
        for (int j = 0; j < 2; ++j)
#pragma unroll
            for (int r = 0; r < 4; ++r) {
                const int rl = i * 16 + quad * 4 + r;
                const int cl = w * 32 + j * 16 + l16;
                const float v = (acc[i][j][r] + bias[nBase + cl]) * mul;
                smem[rl * 136 + cl] = bfbits(v);
            }
    __syncthreads();

    const size_t base3 = (size_t)three * (PHEAD * HEADS);
    if (three < 2) {
        // Q/K frag layout [h][t16][d2][quad*16+l16][8]
#pragma unroll
        for (int pass = 0; pass < 4; ++pass) {
            const int idx = pass * 256 + tid;
            const int rl16 = idx & 15, qc = (idx >> 4) & 7;
            const int hsel = (idx >> 7) & 1, t16l = (idx >> 8) & 3;
            const uint4 d = *(const uint4*)&smem[(t16l * 16 + rl16) * 136 + hsel * 64 + qc * 8];
            const int hh = ((nBase >> 6) + hsel) & 7;
            const int t16 = (mBase >> 4) + t16l;
            const size_t dst = base3 + (size_t)hh * PHEAD +
                (size_t)(((t16 * 2 + (qc >> 2)) * 64 + (qc & 3) * 16 + rl16) * 8);
            *(uint4*)&qkv_out[dst] = d;
        }
    } else {
        // V frag layout [h][k32][dt][quad*16+l16][8] (key-permuted for PV mfma32)
#pragma unroll
        for (int pass = 0; pass < 4; ++pass) {
            const int idx = pass * 256 + tid;
            const int l16t = idx & 15, quadt = (idx >> 4) & 3;
            const int dt = (idx >> 6) & 3, k32l = (idx >> 8) & 1, hsel = (idx >> 9) & 1;
            const int col = hsel * 64 + dt * 16 + l16t;
            unsigned short o8[8];
#pragma unroll
            for (int e = 0; e < 4; ++e) {
                o8[e]     = smem[(k32l * 32 + quadt * 4 + e) * 136 + col];
                o8[e + 4] = smem[(k32l * 32 + 16 + quadt * 4 + e) * 136 + col];
            }
            const int hh = ((nBase >> 6) + hsel) & 7;
            const int k32 = (mBase >> 5) + k32l;
            const size_t dst = base3 + (size_t)hh * PHEAD +
                (size_t)(((k32 * 4 + dt) * 64 + quadt * 16 + l16t) * 8);
            *(uint4*)&qkv_out[dst] = *(uint4*)o8;
        }
    }
}

// ---------------- flash attention v12: PV(g-1) fused behind QK(g), pf carried ---------------
// Body = {loads} -> [QK(g) || PV(g-1)] (32 contiguous MFMA) -> SM(g)->pf.
// Only pf (16 VGPR) crosses the iteration; values bit-identical to flash8.
__global__ __launch_bounds__(256, 2) void flash12_k(
    const unsigned short* __restrict__ qf,
    const unsigned short* __restrict__ kf,
    const unsigned short* __restrict__ vf,
    unsigned short* __restrict__ attn_out)   // [N][C] bf16
{
    __shared__ float ldsO[4][64][68];   // 69632 B
    __shared__ float sml[4][64];

    const int tid = threadIdx.x;
    const int lane = tid & 63;
    const int w = __builtin_amdgcn_readfirstlane(tid >> 6);
    const int l16 = lane & 15, quad = lane >> 4;
    const int h = blockIdx.x, qb = blockIdx.y;     // XCD swizzle: x = head

    const unsigned short* qh = qf + (size_t)h * PHEAD;
    const unsigned short* kb = kf + (size_t)h * PHEAD + w * 65536;   // 1024 keys/wave
    const unsigned short* vb = vf + (size_t)h * PHEAD + w * 65536;

    bf16x8 qfr[4][2];
#pragma unroll
    for (int qt = 0; qt < 4; ++qt)
#pragma unroll
        for (int d2 = 0; d2 < 2; ++d2)
            qfr[qt][d2] = *(const bf16x8*)&qh[((qb * 4 + qt) * 2 + d2) * 512 + lane * 8];

    f32x4 oacc[4][4] = {};   // [dtile][qtile]: O^T  d=quad*4+r, q=l16
    float lv[4] = {};        // per-lane partial l, quad-reduced at end

    bf16x8 kA[4], kB[4], vA[4], vB[4];
    f32x4 s[4][2];           // scores of tile being processed (within-body lifetime)
    bf16x8 pf[4];            // P(g-1), carried across the loop edge

    auto LK = [&](bf16x8* dst, int t) {
#pragma unroll
        for (int i = 0; i < 4; ++i)
            dst[i] = *(const bf16x8*)&kb[t * 2048 + i * 512 + lane * 8];
    };
    auto LV = [&](bf16x8* dst, int t) {
#pragma unroll
        for (int i = 0; i < 4; ++i)
            dst[i] = *(const bf16x8*)&vb[t * 2048 + i * 512 + lane * 8];
    };
    auto QK = [&](bf16x8* ku) {
#pragma unroll
        for (int qt = 0; qt < 4; ++qt) {
            f32x4 a = {};
            a = mfma32(ku[0], qfr[qt][0], a);
            a = mfma32(ku[1], qfr[qt][1], a);
            s[qt][0] = a;
            f32x4 b = {};
            b = mfma32(ku[2], qfr[qt][0], b);
            b = mfma32(ku[3], qfr[qt][1], b);
            s[qt][1] = b;
        }
    };
    auto SM = [&]() {
#pragma unroll
        for (int qt = 0; qt < 4; ++qt) {
            float e0[4], e1[4];
#pragma unroll
            for (int r = 0; r < 4; ++r) {
                e0[r] = __builtin_amdgcn_exp2f(s[qt][0][r]);
                e1[r] = __builtin_amdgcn_exp2f(s[qt][1][r]);
            }
            lv[qt] += ((e0[0] + e0[1]) + (e0[2] + e0[3])) +
                      ((e1[0] + e1[1]) + (e1[2] + e1[3]));
            bf16x8 pb;
#pragma unroll
            for (int r = 0; r < 4; ++r) {
                pb[r]     = (__bf16)e0[r];
                pb[4 + r] = (__bf16)e1[r];
            }
            pf[qt] = pb;
        }
    };
    auto PV = [&](bf16x8* vu) {
#pragma unroll
        for (int dt = 0; dt < 4; ++dt)
#pragma unroll
            for (int qt = 0; qt < 4; ++qt)
                oacc[dt][qt] = mfma32(vu[dt], pf[qt], oacc[dt][qt]);
    };

    // prologue: scores+P of tile 0; V0 and K1 in flight
    LK(kA, 0);
    QK(kA);
    SM();                          // pf = P(0)
    LV(vA, 0);
    LK(kB, 1);

    for (int it = 0; it < 15; ++it) {
        const int g = it * 2 + 1;
        // body g (odd): kcur=kB, knext->kA, vprev=vA, vcur->vB
        LK(kA, g + 1);
        LV(vB, g);
        __builtin_amdgcn_s_setprio(1);
        QK(kB);                    // scores(g)
        PV(vA);                    // oacc += V(g-1) x P(g-1)  [independent of QK]
        __builtin_amdgcn_s_setprio(0);
        SM();                      // pf = P(g)
        // body g+1 (even): kcur=kA, knext->kB, vprev=vB, vcur->vA
        LK(kB, g + 2);
        LV(vA, g + 1);
        __builtin_amdgcn_s_setprio(1);
        QK(kA);                    // scores(g+1)
        PV(vB);                    // oacc += V(g) x P(g)
        __builtin_amdgcn_s_setprio(0);
        SM();                      // pf = P(g+1)
    }
    // body 31 (odd pattern, no K prefetch)
    LV(vB, 31);
    __builtin_amdgcn_s_setprio(1);
    QK(kB);                        // scores(31)
    PV(vA);                        // V(30) x P(30)
    __builtin_amdgcn_s_setprio(0);
    SM();                          // pf = P(31)
    PV(vB);                        // V(31) x P(31)

    // l: reduce lv over the 4 quads (keys are distributed quad-wise)
#pragma unroll
    for (int qt = 0; qt < 4; ++qt) {
        float L = lv[qt];
        L += __shfl_xor(L, 16, 64);
        L += __shfl_xor(L, 32, 64);
        if (quad == 0) sml[w][qt * 16 + l16] = L;
    }
#pragma unroll
    for (int qt = 0; qt < 4; ++qt) {
        const int q = qt * 16 + l16;
#pragma unroll
        for (int dt = 0; dt < 4; ++dt)
            *(f32x4*)&ldsO[w][q][dt * 16 + quad * 4] = oacc[dt][qt];
    }
    __syncthreads();
#pragma unroll
    for (int pass = 0; pass < 2; ++pass) {
        const int idx = pass * 256 + tid;
        const int q = idx >> 3, dseg = (idx & 7) * 8;
        const float L = sml[0][q] + sml[1][q] + sml[2][q] + sml[3][q];
        const float inv = 1.f / L;
        unsigned short o8[8];
#pragma unroll
        for (int i = 0; i < 8; ++i) {
            const float v = ldsO[0][q][dseg + i] + ldsO[1][q][dseg + i] +
                            ldsO[2][q][dseg + i] + ldsO[3][q][dseg + i];
            o8[i] = bfbits(v * inv);
        }
        *(uint4*)&attn_out[(size_t)(qb * 64 + q) * CDIM + h * DHEAD + dseg] = *(uint4*)o8;
    }
}

// ---------------- proj GEMM: 64x64, dbuf gload_lds, bank-swizzled reads --------------------
__global__ __launch_bounds__(256) void gemm_proj(
    const unsigned short* __restrict__ A,   // attn [4096][512] bf16
    const unsigned short* __restrict__ Bm,  // Wproj bf16 [512][512]
    const float* __restrict__ bias,
    float* __restrict__ c_out)              // [4096][512] fp32
{
    __shared__ __align__(16) unsigned short smem[2 * 4096];  // 16384 B

    const int tid = threadIdx.x;
    const int mBase = blockIdx.y * 64, nBase = blockIdx.x * 64;
    const int lane = tid & 63;
    const int w = __builtin_amdgcn_readfirstlane(tid >> 6);
    const int l16 = lane & 15, quad = lane >> 4;

    const int srow = tid >> 2;
    const int scol = ((tid & 3) ^ ((tid >> 3) & 3)) * 8;     // pre-swizzled source granule
    const unsigned short* gA = &A[(size_t)(mBase + srow) * CDIM + scol];
    const unsigned short* gB = &Bm[(size_t)(nBase + srow) * CDIM + scol];

    const int qs = (quad ^ ((l16 >> 1) & 3)) * 8;            // swizzled read granule

    f32x4 acc[4] = {};   // wave w owns cols [w*16, w*16+16), all 64 rows

    gload16(gA, &smem[tid * 8]);
    gload16(gB, &smem[2048 + tid * 8]);

    int cur = 0;
    for (int kt = 0; kt < CDIM; kt += 32) {
        __syncthreads();
        if (kt + 32 < CDIM) {
            const int nb = (cur ^ 1) * 4096;
            gload16(gA + kt + 32, &smem[nb + tid * 8]);
            gload16(gB + kt + 32, &smem[nb + 2048 + tid * 8]);
        }
        const unsigned short* lA = &smem[cur * 4096];
        const unsigned short* lB = &smem[cur * 4096 + 2048];

        bf16x8 af[4], bfr;
#pragma unroll
        for (int i = 0; i < 4; ++i)
            af[i] = *(const bf16x8*)&lA[(i * 16 + l16) * 32 + qs];
        bfr = *(const bf16x8*)&lB[(w * 16 + l16) * 32 + qs];
#pragma unroll
        for (int i = 0; i < 4; ++i)
            acc[i] = mfma32(af[i], bfr, acc[i]);
        cur ^= 1;
    }

#pragma unroll
    for (int i = 0; i < 4; ++i)
#pragma unroll
        for (int r = 0; r < 4; ++r) {
            const int grow = mBase + i * 16 + quad * 4 + r;
            const int gcol = nBase + w * 16 + l16;
            c_out[(size_t)grow * CDIM + gcol] = acc[i][r] + bias[gcol];
        }
}

extern "C" void kernel_launch(void* const* d_in, const int* in_sizes, int n_in,
                              void* d_out, int out_size, void* d_ws, size_t ws_size,
                              hipStream_t stream) {
    const float* x       = (const float*)d_in[0];
    const float* scale_p = (const float*)d_in[3];
    const float* Wqkv    = (const float*)d_in[4];
    const float* bqkv    = (const float*)d_in[5];
    const float* Wproj   = (const float*)d_in[6];
    const float* bproj   = (const float*)d_in[7];
    float* out = (float*)d_out;

    char* ws = (char*)d_ws;
    const size_t OFF_QKV  = 0;                        // 3*8*PHEAD bf16 = 12 MB
    const size_t OFF_ATTN = 12582912;                 // 4096*512 bf16  =  4 MB
    const size_t OFF_XB   = 16777216;                 // x bf16          =  4 MB
    const size_t OFF_WQB  = 20971520;                 // Wqkv bf16       = 1.5 MB
    const size_t OFF_WPB  = 22544384;                 // Wproj bf16      = 0.5 MB
    const size_t NEEDED   = OFF_WPB + 524288;         // 23 MB
    if (ws_size < NEEDED) return;

    unsigned short* qkvb  = (unsigned short*)(ws + OFF_QKV);
    unsigned short* attnb = (unsigned short*)(ws + OFF_ATTN);
    unsigned short* xb    = (unsigned short*)(ws + OFF_XB);
    unsigned short* wqb   = (unsigned short*)(ws + OFF_WQB);
    unsigned short* wpb   = (unsigned short*)(ws + OFF_WPB);

    cast3_k<<<1536, 256, 0, stream>>>(x, Wqkv, Wproj, xb, wqb, wpb);

    gemm_qkv<<<dim3(12, 64), 256, 0, stream>>>(xb, wqb, bqkv, scale_p, qkvb);

    const unsigned short* qfr = qkvb;
    const unsigned short* kfr = qkvb + (size_t)PHEAD * HEADS;
    const unsigned short* vfr = qkvb + (size_t)2 * PHEAD * HEADS;
    flash12_k<<<dim3(8, 64), 256, 0, stream>>>(qfr, kfr, vfr, attnb);

    gemm_proj<<<dim3(8, 64), 256, 0, stream>>>(attnb, wpb, bproj, out);
}